// Round 6
// baseline (7079.363 us; speedup 1.0000x reference)
//
#include <hip/hip_runtime.h>

// Dims
constexpr int TSTEPS = 512;
constexpr int FDIM   = 128;
constexpr int HDIM   = 256;
constexpr int G4H    = 1024;   // 4*H
constexpr int BATCH  = 256;
constexpr int NB     = 86;     // 84 blocks x 3 rows + 2 x 2 rows
constexpr int NKP    = 192;    // k-pairs: 384 merged K / 2 (kp<128 = rker, >=128 = kern)

typedef float    f32x2 __attribute__((ext_vector_type(2)));
typedef float    f32x4 __attribute__((ext_vector_type(4)));
typedef _Float16 h2    __attribute__((ext_vector_type(2)));
typedef _Float16 f16x8 __attribute__((ext_vector_type(8)));
typedef unsigned int u32;

#if defined(__has_builtin)
#if __has_builtin(__builtin_amdgcn_fdot2)
#define FDOT2(a, b, c) __builtin_amdgcn_fdot2((a), (b), (c), false)
#endif
#endif
#ifndef FDOT2
#define FDOT2(a, b, c) ((c) + (float)(a)[0] * (float)(b)[0] + (float)(a)[1] * (float)(b)[1])
#endif

__device__ __forceinline__ float sigmf(float z) { return 1.f / (1.f + __expf(-z)); }
__device__ __forceinline__ float tanhf_fast(float z) {
    float a = fabsf(z);
    float e = __expf(-2.f * a);
    float r = (1.f - e) / (1.f + e);
    return z < 0.f ? -r : r;
}

// Repack weights to fp16 k-pairs: wpk[kp][c] = (w[2kp][c], w[2kp+1][c]).
// kp<128 from rker (k=0..255), kp>=128 from kern (k=256..383). 768 KB.
extern "C" __global__ void __launch_bounds__(256)
conv_wpk(const float* __restrict__ kern, const float* __restrict__ rker,
         u32* __restrict__ wpk)
{
    for (int i = blockIdx.x * 256 + threadIdx.x; i < NKP * G4H; i += gridDim.x * 256) {
        const int kp = i >> 10, c = i & 1023;
        float a, b;
        if (kp < 128) {
            a = rker[(size_t)(2 * kp) * G4H + c];
            b = rker[(size_t)(2 * kp + 1) * G4H + c];
        } else {
            const int k0 = (kp - 128) * 2;
            a = kern[(size_t)k0 * G4H + c];
            b = kern[(size_t)(k0 + 1) * G4H + c];
        }
        union { h2 p; u32 u; } cv;
        cv.p = h2{(_Float16)a, (_Float16)b};
        wpk[i] = cv.u;
    }
}

// Zero-sync LSTM, v_dot2 + partial VGPR-resident weights.
// Round-5 analysis: port (60 B/cyc/CU) and VALU were ~equal and serialized.
// dot2 kills cvts + halves FMAs (VALU 13.8k->5.8k cyc); 16/48 k-pairs resident
// in regs cuts streamed bytes 768->512 KB (port 13.1k->8.7k cyc); 4-deep
// rotating prefetch issued before the barrier keeps the port saturated.
// 86 blocks x 1024 threads; wave: q=wave>>2 (kp-quarter), gate=wave&3;
// thread owns 4 consecutive columns (16B/kp loads).
extern "C" __global__ void __launch_bounds__(1024, 1)
lstm_dot2(const float* __restrict__ x, const u32* __restrict__ wpk,
          const float* __restrict__ w1, const float* __restrict__ b1,
          const float* __restrict__ w2, const float* __restrict__ b2,
          float* __restrict__ out)
{
    const int b    = blockIdx.x;
    const int base = (b < 84) ? 3 * b : 252 + 2 * (b - 84);
    const int nval = (b < 84) ? 3 : 2;
    const int tid  = threadIdx.x;
    const int wave = tid >> 6;
    const int lane = tid & 63;
    const int q    = wave >> 2;               // kp in [48q, 48q+48)
    const int gate = wave & 3;
    const int coff = gate * 256 + lane * 4;

    __shared__ u32   hpk[NKP * 4];            // [kp][row] fp16 pairs; rows 0..2 live, 3 pad
    __shared__ float zp[4][3][G4H];           // quarter partials, 48 KB
    __shared__ float hid[3][104];

    // h(0) = 0: h-region only (kp<128). Pad rows never enter the dots; x-region
    // is fully staged each step before B1 (no race with this init).
    if (tid < 512) hpk[tid] = 0;

    const u32* wp  = wpk + coff;
    const int  kp0 = q * 48;

    // ---- Resident: first 16 kp of this wave's range (64 VGPRs/thread, 256 KB/CU)
    f16x8 wres[16];
#pragma unroll
    for (int i = 0; i < 16; ++i)
        wres[i] = *reinterpret_cast<const f16x8*>(wp + (size_t)(kp0 + i) * G4H);

    const int rP = tid >> 8, uP = tid & 255;  // P2 mapping
    float cst = 0.f;

    // x staging: waves 0..2 -> row=wave, lane = feature-pair index (64 pairs)
    const float* xp = x + ((size_t)min(base + (wave < 3 ? wave : 0), BATCH - 1) * TSTEPS) * FDIM
                        + 2 * lane;

#pragma unroll 1
    for (int t = 0; t < TSTEPS; ++t) {
        // ---- Prefetch first streamed chunk BEFORE the barrier (in flight across B1)
        f16x8 pf[4];
#pragma unroll
        for (int j = 0; j < 4; ++j)
            pf[j] = *reinterpret_cast<const f16x8*>(wp + (size_t)(kp0 + 16 + j) * G4H);

        // ---- Stage x(t) as fp16 pairs -> hpk[128+fp][row]
        if (tid < 192) {
            const f32x2 xv = *reinterpret_cast<const f32x2*>(xp + (size_t)t * FDIM);
            union { h2 p; u32 u; } cv;
            cv.p = h2{(_Float16)xv[0], (_Float16)xv[1]};
            hpk[(128 + lane) * 4 + wave] = cv.u;
        }
        __syncthreads();  // B1: x+h staged; zp(t-1) consumed

        float acc[3][4];
#pragma unroll
        for (int r = 0; r < 3; ++r)
#pragma unroll
            for (int j = 0; j < 4; ++j) acc[r][j] = 0.f;

        // ---- Streamed 32 kp, rotating 4-deep prefetch
#pragma unroll
        for (int i = 0; i < 32; ++i) {
            const f16x8 W = pf[i & 3];
            if (i < 28)
                pf[i & 3] = *reinterpret_cast<const f16x8*>(wp + (size_t)(kp0 + 20 + i) * G4H);
            const f16x8 H = *reinterpret_cast<const f16x8*>(&hpk[(kp0 + 16 + i) * 4]);
            const h2 h0 = {H[0], H[1]}, h1v = {H[2], H[3]}, h2v = {H[4], H[5]};
#pragma unroll
            for (int j = 0; j < 4; ++j) {
                const h2 wj = {W[2 * j], W[2 * j + 1]};
                acc[0][j] = FDOT2(wj, h0, acc[0][j]);
                acc[1][j] = FDOT2(wj, h1v, acc[1][j]);
                acc[2][j] = FDOT2(wj, h2v, acc[2][j]);
            }
        }
        // ---- Resident 16 kp (no VMEM)
#pragma unroll
        for (int i = 0; i < 16; ++i) {
            const f16x8 W = wres[i];
            const f16x8 H = *reinterpret_cast<const f16x8*>(&hpk[(kp0 + i) * 4]);
            const h2 h0 = {H[0], H[1]}, h1v = {H[2], H[3]}, h2v = {H[4], H[5]};
#pragma unroll
            for (int j = 0; j < 4; ++j) {
                const h2 wj = {W[2 * j], W[2 * j + 1]};
                acc[0][j] = FDOT2(wj, h0, acc[0][j]);
                acc[1][j] = FDOT2(wj, h1v, acc[1][j]);
                acc[2][j] = FDOT2(wj, h2v, acc[2][j]);
            }
        }

        // ---- Partials: lane-consecutive b128 stores, conflict-free
#pragma unroll
        for (int r = 0; r < 3; ++r)
            *reinterpret_cast<f32x4*>(&zp[q][r][coff]) =
                f32x4{acc[r][0], acc[r][1], acc[r][2], acc[r][3]};
        __syncthreads();  // B2

        // ---- P2: combine quarters, gates, cell update, h(t+1) -> hpk (fp16 half-write)
        if (tid < 768) {
            float z0 = 0.f, z1 = 0.f, z2 = 0.f, z3 = 0.f;
#pragma unroll
            for (int qq = 0; qq < 4; ++qq) {
                z0 += zp[qq][rP][0 * 256 + uP];
                z1 += zp[qq][rP][1 * 256 + uP];
                z2 += zp[qq][rP][2 * 256 + uP];
                z3 += zp[qq][rP][3 * 256 + uP];
            }
            cst = sigmf(z1) * cst + sigmf(z0) * tanhf_fast(z2);
            const float hnew = sigmf(z3) * tanhf_fast(cst);
            ((_Float16*)hpk)[((uP >> 1) * 4 + rP) * 2 + (uP & 1)] = (_Float16)hnew;
        }
        // No barrier: B1(next) orders hpk writes / zp reads vs next step.
    }
    __syncthreads();

    // ---- Fused head: out[row] = relu(h@w1+b1)@w2 + b2 (h fp16 from hpk)
    if (tid < 300) {
        const int r = tid / 100, j = tid - r * 100;
        if (r < nval) {
            float a = b1[j];
            const _Float16* hph = (const _Float16*)hpk;
#pragma unroll 8
            for (int k = 0; k < HDIM; ++k)
                a += (float)hph[(k >> 1) * 8 + r * 2 + (k & 1)] * w1[k * 100 + j];
            hid[r][j] = fmaxf(a, 0.f);
        }
    }
    __syncthreads();
    if (tid < 3 && tid < nval) {
        float v = b2[0];
#pragma unroll 4
        for (int j = 0; j < 100; ++j) v += hid[tid][j] * w2[j];
        out[base + tid] = v;
    }
}

extern "C" void kernel_launch(void* const* d_in, const int* in_sizes, int n_in,
                              void* d_out, int out_size, void* d_ws, size_t ws_size,
                              hipStream_t stream)
{
    const float* x    = (const float*)d_in[0];
    const float* kern = (const float*)d_in[1];
    const float* rker = (const float*)d_in[2];
    const float* w1   = (const float*)d_in[3];
    const float* b1   = (const float*)d_in[4];
    const float* w2   = (const float*)d_in[5];
    const float* b2   = (const float*)d_in[6];
    float* out = (float*)d_out;

    u32* wpk = (u32*)d_ws;  // 768 KB (round-5 full16 branch ran => ws_size >= 768 KB)

    conv_wpk<<<dim3(768), dim3(256), 0, stream>>>(kern, rker, wpk);
    lstm_dot2<<<dim3(NB), dim3(1024), 0, stream>>>(x, wpk, w1, b1, w2, b2, out);
}